// Round 8
// baseline (229.274 us; speedup 1.0000x reference)
//
#include <hip/hip_runtime.h>
#include <cstdint>

// ---------- types ----------
typedef __attribute__((ext_vector_type(4))) float f32x4;
typedef __attribute__((ext_vector_type(8))) __bf16 bf16x8;
typedef __attribute__((ext_vector_type(8))) unsigned short u16x8;

// ---------- helpers ----------
__device__ __forceinline__ unsigned short f2bf(float f) {
    union { float f; unsigned u; } v; v.f = f;
    unsigned u = v.u + 0x7FFFu + ((v.u >> 16) & 1u);   // RNE
    return (unsigned short)(u >> 16);
}
__device__ __forceinline__ float bf2f(unsigned short h) {
    union { unsigned u; float f; } v; v.u = ((unsigned)h) << 16;
    return v.f;
}

__device__ __forceinline__ void gld_lds16(const void* g, void* l) {
    auto gp = reinterpret_cast<const __attribute__((address_space(1))) unsigned int*>(
        reinterpret_cast<uintptr_t>(g));
    auto lp = reinterpret_cast<__attribute__((address_space(3))) unsigned int*>(
        reinterpret_cast<uintptr_t>(l));
    __builtin_amdgcn_global_load_lds(gp, lp, 16, 0, 0);
}

#define MFMA_BF16(a, b, c) __builtin_amdgcn_mfma_f32_16x16x32_bf16((a), (b), (c), 0, 0, 0)

// ================= 256x256-tile 8-phase GEMM core, C = A * B^T =================
// 8 waves (512 thr), wave grid 2(M)x4(N): wave tile 128x64, acc[8][4] f32x4.
// BK=64. LDS: lA/lB each 2 bufs x 256x64 bf16 (linear rows, XOR chunk swizzle) = 128 KiB.
// Per K-tile: 4 phases x {ds_read quad | stage half-tile | barrier | 16 MFMA | barrier}.
// Prefetch distance 2 K-tiles; ONE s_waitcnt vmcnt(4) per K-tile (at phase-3 end), never 0.
// Stage ledger (T = current K-tile, buf c = T&1):
//   p0: stage A-h0(T+1)->buf c^1   (A reads of c^1 finished at T-1 p3 barrier)
//   p1: stage A-h1(T+1)->buf c^1 ; stage B-h0(T+2)->buf c  (B of c fully read in p0)
//   p2: stage B-h1(T+2)->buf c
//   p3: after MFMA: vmcnt(4) drains through A-h1(T+1), leaves B(T+2) pair in flight.
template<int BF16OUT>
__device__ __forceinline__ void gemm256(
    const unsigned short* __restrict__ A, int lda,
    const unsigned short* __restrict__ B, int ldb,
    void* __restrict__ C, int ldc,
    int ktiles,
    unsigned short* lA, unsigned short* lB)   // each 32768 shorts (2 x 16384)
{
    const int t = threadIdx.x;
    const int l = t & 63;
    const int w = t >> 6;
    const int wm = w >> 2, wn = w & 3;         // 2(M) x 4(N)

    f32x4 acc[8][4];
#pragma unroll
    for (int i = 0; i < 8; ++i)
#pragma unroll
        for (int j = 0; j < 4; ++j)
#pragma unroll
            for (int e = 0; e < 4; ++e) acc[i][j][e] = 0.f;

    // stage one half-tile (128 rows x 64 bf16 = 16 KB): 2 x gld_lds16 per thread
    auto stage = [&](const unsigned short* __restrict__ G, int ld, unsigned short* L,
                     int p, int h, int kt) {
        const int k0 = kt << 6;
#pragma unroll
        for (int i = 0; i < 2; ++i) {
            const int flat = t + (i << 9);            // 0..1023
            const int row  = (h << 7) + (flat >> 3);  // h*128 + 0..127
            const int sc   = (flat & 7) ^ (row & 7);  // pre-swizzled source chunk
            gld_lds16(G + (size_t)row * ld + k0 + (sc << 3),
                      L + (p << 14) + (h << 13) + (flat << 3));
        }
    };

    auto rdA = [&](int p, int mf, int kk) -> bf16x8 {
        const int r = (wm << 7) + (mf << 4) + (l & 15);
        const int c = (kk << 5) + ((l >> 4) << 3);
        const int ad = (((r << 6) + c) ^ ((r & 7) << 3)) + (p << 14);
        return *(const bf16x8*)(lA + ad);
    };
    auto rdB = [&](int p, int nf, int kk) -> bf16x8 {
        const int r = (wn << 6) + (nf << 4) + (l & 15);
        const int c = (kk << 5) + ((l >> 4) << 3);
        const int ad = (((r << 6) + c) ^ ((r & 7) << 3)) + (p << 14);
        return *(const bf16x8*)(lB + ad);
    };

    // prologue: B(0),A(0) -> buf0 ; B(1) -> buf1. vmcnt(4) leaves B(1) pair in flight.
    const int kt1 = (ktiles > 1) ? 1 : 0;
    stage(B, ldb, lB, 0, 0, 0); stage(B, ldb, lB, 0, 1, 0);
    stage(A, lda, lA, 0, 0, 0); stage(A, lda, lA, 0, 1, 0);
    stage(B, ldb, lB, 1, 0, kt1); stage(B, ldb, lB, 1, 1, kt1);
    asm volatile("s_waitcnt vmcnt(4)" ::: "memory");
    __builtin_amdgcn_s_barrier();

#define MMA_PHASE(MF0, A00, A01, A10, A11)                                    \
    __builtin_amdgcn_s_setprio(1);                                            \
    _Pragma("unroll")                                                         \
    for (int nf = 0; nf < 4; ++nf) {                                          \
        acc[MF0][nf]     = MFMA_BF16(A00, bq[nf][0], acc[MF0][nf]);           \
        acc[MF0][nf]     = MFMA_BF16(A01, bq[nf][1], acc[MF0][nf]);           \
        acc[MF0 + 1][nf] = MFMA_BF16(A10, bq[nf][0], acc[MF0 + 1][nf]);       \
        acc[MF0 + 1][nf] = MFMA_BF16(A11, bq[nf][1], acc[MF0 + 1][nf]);       \
    }                                                                         \
    __builtin_amdgcn_s_setprio(0);

    for (int kt = 0; kt < ktiles; ++kt) {
        const int p = kt & 1;
        const int ktA = (kt + 1 < ktiles) ? kt + 1 : ktiles - 1;
        const int ktB = (kt + 2 < ktiles) ? kt + 2 : ktiles - 1;

        // ---- phase 0: all B frags + A mf{0,1}; stage A-h0(kt+1) ----
        bf16x8 bq[4][2];
#pragma unroll
        for (int nf = 0; nf < 4; ++nf) {
            bq[nf][0] = rdB(p, nf, 0);
            bq[nf][1] = rdB(p, nf, 1);
        }
        bf16x8 a00 = rdA(p, 0, 0), a01 = rdA(p, 0, 1);
        bf16x8 a10 = rdA(p, 1, 0), a11 = rdA(p, 1, 1);
        stage(A, lda, lA, p ^ 1, 0, ktA);
        __builtin_amdgcn_s_barrier();
        MMA_PHASE(0, a00, a01, a10, a11)
        __builtin_amdgcn_s_barrier();

        // ---- phase 1: A mf{2,3}; stage A-h1(kt+1), B-h0(kt+2) ----
        a00 = rdA(p, 2, 0); a01 = rdA(p, 2, 1);
        a10 = rdA(p, 3, 0); a11 = rdA(p, 3, 1);
        stage(A, lda, lA, p ^ 1, 1, ktA);
        stage(B, ldb, lB, p, 0, ktB);
        __builtin_amdgcn_s_barrier();
        MMA_PHASE(2, a00, a01, a10, a11)
        __builtin_amdgcn_s_barrier();

        // ---- phase 2: A mf{4,5}; stage B-h1(kt+2) ----
        a00 = rdA(p, 4, 0); a01 = rdA(p, 4, 1);
        a10 = rdA(p, 5, 0); a11 = rdA(p, 5, 1);
        stage(B, ldb, lB, p, 1, ktB);
        __builtin_amdgcn_s_barrier();
        MMA_PHASE(4, a00, a01, a10, a11)
        __builtin_amdgcn_s_barrier();

        // ---- phase 3: A mf{6,7}; vmcnt(4) then publish barrier ----
        a00 = rdA(p, 6, 0); a01 = rdA(p, 6, 1);
        a10 = rdA(p, 7, 0); a11 = rdA(p, 7, 1);
        __builtin_amdgcn_s_barrier();
        MMA_PHASE(6, a00, a01, a10, a11)
        asm volatile("s_waitcnt vmcnt(4)" ::: "memory");
        __builtin_amdgcn_s_barrier();
    }
#undef MMA_PHASE

    // epilogue: D[row][col], col=lane&15, row=(lane>>4)*4+reg (m89-verified)
#pragma unroll
    for (int mf = 0; mf < 8; ++mf)
#pragma unroll
        for (int nf = 0; nf < 4; ++nf)
#pragma unroll
            for (int j = 0; j < 4; ++j) {
                const int row = (wm << 7) + (mf << 4) + ((l >> 4) << 2) + j;
                const int col = (wn << 6) + (nf << 4) + (l & 15);
                const float v = acc[mf][nf][j];
                if (BF16OUT)
                    ((unsigned short*)C)[(size_t)row * ldc + col] = f2bf(v);
                else
                    ((float*)C)[(size_t)row * ldc + col] = v;
            }
}

// ================= legacy 128x128 2-phase core (kept for causal PV) =================
template<int BF16OUT>
__device__ __forceinline__ void gemm8(
    const unsigned short* __restrict__ A, int lda,
    const unsigned short* __restrict__ B, int ldb,
    void* __restrict__ C, int ldc,
    int ktiles,
    unsigned short* lA, unsigned short* lB)   // each [2][128][64] shorts = 2x16KB
{
    const int t = threadIdx.x;
    const int l = t & 63;
    const int w = t >> 6;
    const int wr = w >> 1, wc = w & 1;   // 4x2 wave grid

    f32x4 acc[2][4];
#pragma unroll
    for (int i = 0; i < 2; ++i)
#pragma unroll
        for (int j = 0; j < 4; ++j)
#pragma unroll
            for (int e = 0; e < 4; ++e) acc[i][j][e] = 0.f;

    auto stage = [&](int p, int kt) {
        const int k0 = kt << 6;
#pragma unroll
        for (int i = 0; i < 2; ++i) {
            const int flat = t + (i << 9);
            const int row = flat >> 3;
            const int sc = (flat & 7) ^ (row & 7);
            gld_lds16(A + (size_t)row * lda + k0 + (sc << 3), lA + (p << 13) + (flat << 3));
            gld_lds16(B + (size_t)row * ldb + k0 + (sc << 3), lB + (p << 13) + (flat << 3));
        }
    };

    auto compute = [&](int p) {
#pragma unroll
        for (int kk = 0; kk < 2; ++kk) {
            bf16x8 af[2], bfr[4];
            const int c = (kk << 5) + ((l >> 4) << 3);
#pragma unroll
            for (int mf = 0; mf < 2; ++mf) {
                const int r = (wr << 5) + (mf << 4) + (l & 15);
                const int ad = (((r << 6) + c) ^ ((r & 7) << 3)) + (p << 13);
                af[mf] = *(const bf16x8*)(lA + ad);
            }
#pragma unroll
            for (int nf = 0; nf < 4; ++nf) {
                const int r = (wc << 6) + (nf << 4) + (l & 15);
                const int ad = (((r << 6) + c) ^ ((r & 7) << 3)) + (p << 13);
                bfr[nf] = *(const bf16x8*)(lB + ad);
            }
            __builtin_amdgcn_s_setprio(1);
#pragma unroll
            for (int mf = 0; mf < 2; ++mf)
#pragma unroll
                for (int nf = 0; nf < 4; ++nf)
                    acc[mf][nf] = MFMA_BF16(af[mf], bfr[nf], acc[mf][nf]);
            __builtin_amdgcn_s_setprio(0);
        }
    };

    stage(0, 0);
    __syncthreads();
    int p = 0;
    for (int kt = 0; kt < ktiles - 1; ++kt) {
        stage(p ^ 1, kt + 1);
        compute(p);
        __syncthreads();
        p ^= 1;
    }
    compute(p);

#pragma unroll
    for (int mf = 0; mf < 2; ++mf)
#pragma unroll
        for (int nf = 0; nf < 4; ++nf)
#pragma unroll
            for (int j = 0; j < 4; ++j) {
                const int row = (wr << 5) + (mf << 4) + ((l >> 4) << 2) + j;
                const int col = (wc << 6) + (nf << 4) + (l & 15);
                const float v = acc[mf][nf][j];
                if (BF16OUT)
                    ((unsigned short*)C)[(size_t)row * ldc + col] = f2bf(v);
                else
                    ((float*)C)[(size_t)row * ldc + col] = v;
            }
}

// ---------- wrappers ----------
// merged projections: blocks 0..255 = QK (M=8192,N=2048), 256..383 = Vt (M=1024,N=8192)
__global__ __launch_bounds__(512, 2) void k_proj256(
    const unsigned short* __restrict__ xb, const unsigned short* __restrict__ wtqk,
    const unsigned short* __restrict__ wtv,
    unsigned short* __restrict__ qk, unsigned short* __restrict__ vt)
{
    __shared__ unsigned short lA[32768], lB[32768];
    const int h = blockIdx.x;
    const int lgc = (h & 7) * 48 + (h >> 3);   // XCD swizzle, 384/8=48
    if (lgc < 256) {
        const int by = lgc >> 3, bx = lgc & 7;
        gemm256<1>(xb + (size_t)by * 256 * 1024, 1024,
                   wtqk + (size_t)bx * 256 * 1024, 1024,
                   qk + (size_t)by * 256 * 2048 + bx * 256, 2048,
                   16, lA, lB);
    } else {
        const int l2 = lgc - 256;
        const int dn = l2 & 3, tn = l2 >> 2;
        gemm256<1>(wtv + (size_t)dn * 256 * 1024, 1024,
                   xb + (size_t)tn * 256 * 1024, 1024,
                   vt + (size_t)dn * 256 * 8192 + tn * 256, 8192,
                   16, lA, lB);
    }
}

// causal scores at 256^2 tiles: triangular block index, Q = qk cols [0,1024), K = cols [1024,2048)
__global__ __launch_bounds__(512, 2) void k_scores256(
    const unsigned short* __restrict__ qk, unsigned short* __restrict__ S)
{
    __shared__ unsigned short lA[32768], lB[32768];
    const int b = blockIdx.z;
    const int tidx = blockIdx.x;               // 0..35
    int qt2 = 0;
    while ((qt2 + 1) * (qt2 + 2) / 2 <= tidx) ++qt2;
    const int kt2 = tidx - qt2 * (qt2 + 1) / 2;
    gemm256<1>(qk + ((size_t)b * 2048 + qt2 * 256) * 2048, 2048,
               qk + ((size_t)b * 2048 + kt2 * 256) * 2048 + 1024, 2048,
               S + (size_t)b * 4194304 + (size_t)qt2 * 256 * 2048 + kt2 * 256, 2048,
               16, lA, lB);
}

// PV: out[b,q][d] = sum_{t'<=q} P[b,q][t'] * Vt[d][b*2048+t']; paired qt tiles (legacy core)
__global__ __launch_bounds__(512, 4) void k_pv(
    const unsigned short* __restrict__ P, const unsigned short* __restrict__ Vt,
    float* __restrict__ out)
{
    const int dn = blockIdx.x, pr = blockIdx.y, b = blockIdx.z;
    __shared__ unsigned short lA[16384], lB[16384];
    const int q1 = pr, q2 = 15 - pr;
    gemm8<0>(P + (size_t)b * 4194304 + (size_t)q1 * 128 * 2048, 2048,
             Vt + (size_t)dn * 128 * 8192 + b * 2048, 8192,
             out + ((size_t)b * 2048 + q1 * 128) * 1024 + dn * 128, 1024,
             (q1 + 1) * 2, lA, lB);
    __syncthreads();
    gemm8<0>(P + (size_t)b * 4194304 + (size_t)q2 * 128 * 2048, 2048,
             Vt + (size_t)dn * 128 * 8192 + b * 2048, 8192,
             out + ((size_t)b * 2048 + q2 * 128) * 1024 + dn * 128, 1024,
             (q2 + 1) * 2, lA, lB);
}

// ---------- cast / transpose ----------
__global__ __launch_bounds__(256) void k_cast_bf16(
    const float* __restrict__ in, unsigned short* __restrict__ out, int n8)
{
    const int i = blockIdx.x * 256 + threadIdx.x;
    if (i >= n8) return;
    const float4* p = (const float4*)in + (size_t)i * 2;
    const float4 a = p[0], b = p[1];
    u16x8 r;
    r[0] = f2bf(a.x); r[1] = f2bf(a.y); r[2] = f2bf(a.z); r[3] = f2bf(a.w);
    r[4] = f2bf(b.x); r[5] = f2bf(b.y); r[6] = f2bf(b.z); r[7] = f2bf(b.w);
    *(u16x8*)(out + (size_t)i * 8) = r;
}

// z=0: Wq^T * (1/32) -> wtqk rows [0,1024); z=1: Wk^T -> wtqk rows [1024,2048); z=2: Wv^T -> wtv
__global__ __launch_bounds__(256) void k_transpose3(
    const float* __restrict__ Wq, const float* __restrict__ Wk, const float* __restrict__ Wv,
    unsigned short* __restrict__ wtqk, unsigned short* __restrict__ wtv)
{
    __shared__ float tile[32][33];
    const int z = blockIdx.z;
    const float* in = (z == 0) ? Wq : (z == 1) ? Wk : Wv;
    unsigned short* out = (z < 2) ? (wtqk + (size_t)z * 1048576) : wtv;
    const float s = (z == 0) ? 0.03125f : 1.0f;
    const int bx = blockIdx.x * 32, by = blockIdx.y * 32;
    const int tx = threadIdx.x, ty = threadIdx.y;
    for (int r = ty; r < 32; r += 8)
        tile[r][tx] = in[(size_t)(by + r) * 1024 + bx + tx];
    __syncthreads();
    for (int r = ty; r < 32; r += 8)
        out[(size_t)(bx + r) * 1024 + by + tx] = f2bf(tile[tx][r] * s);
}

// ---------- causal row softmax over bf16 scores, in place, one wave per row ----------
__global__ __launch_bounds__(256) void k_softmax(unsigned short* __restrict__ S)
{
    const int w = threadIdx.x >> 6, l = threadIdx.x & 63;
    const int r = blockIdx.x * 4 + w;
    const int b = r >> 11, lr = r & 2047;
    unsigned short* row = S + ((size_t)b << 22) + ((size_t)lr << 11);
    const int edge = ((lr >> 7) + 1) << 7;      // 128-granular diag edge (PV reads only < edge)

    float v[32];
#pragma unroll
    for (int i = 0; i < 4; ++i) {
        const int c0 = (l << 3) + (i << 9);
        if (c0 < edge) {
            const u16x8 u = *(const u16x8*)(row + c0);
#pragma unroll
            for (int j = 0; j < 8; ++j)
                v[(i << 3) + j] = (c0 + j <= lr) ? bf2f(u[j]) : -3.0e38f;
        } else {
#pragma unroll
            for (int j = 0; j < 8; ++j) v[(i << 3) + j] = -3.0e38f;
        }
    }
    float m = v[0];
#pragma unroll
    for (int k = 1; k < 32; ++k) m = fmaxf(m, v[k]);
#pragma unroll
    for (int s = 32; s; s >>= 1) m = fmaxf(m, __shfl_xor(m, s, 64));
    float sum = 0.f;
#pragma unroll
    for (int k = 0; k < 32; ++k) { const float e = __expf(v[k] - m); v[k] = e; sum += e; }
#pragma unroll
    for (int s = 32; s; s >>= 1) sum += __shfl_xor(sum, s, 64);
    const float inv = 1.f / sum;
#pragma unroll
    for (int i = 0; i < 4; ++i) {
        const int c0 = (l << 3) + (i << 9);
        if (c0 < edge) {
            u16x8 o;
#pragma unroll
            for (int j = 0; j < 8; ++j) o[j] = f2bf(v[(i << 3) + j] * inv);
            *(u16x8*)(row + c0) = o;
        }
    }
}

// ---------- launch ----------
extern "C" void kernel_launch(void* const* d_in, const int* in_sizes, int n_in,
                              void* d_out, int out_size, void* d_ws, size_t ws_size,
                              hipStream_t stream)
{
    (void)in_sizes; (void)n_in; (void)out_size; (void)ws_size;
    const float* x  = (const float*)d_in[0];
    const float* Wq = (const float*)d_in[1];
    const float* Wk = (const float*)d_in[2];
    const float* Wv = (const float*)d_in[3];
    float* out = (float*)d_out;

    char* w = (char*)d_ws;
    unsigned short* xb   = (unsigned short*)(w);                  // 16 MiB
    unsigned short* wtqk = (unsigned short*)(w + 16777216);       //  4 MiB (Wq^T/32 | Wk^T)
    unsigned short* wtv  = (unsigned short*)(w + 20971520);       //  2 MiB
    unsigned short* QK   = (unsigned short*)(w + 23068672);       // 32 MiB (Q | K per row)
    unsigned short* Vt   = (unsigned short*)(w + 56623104);       // 16 MiB
    unsigned short* S    = (unsigned short*)(w + 73400320);       // 32 MiB (S then P in place)

    k_cast_bf16<<<4096, 256, 0, stream>>>(x, xb, 1048576);
    k_transpose3<<<dim3(32, 32, 3), dim3(32, 8), 0, stream>>>(Wq, Wk, Wv, wtqk, wtv);

    k_proj256<<<384, 512, 0, stream>>>(xb, wtqk, wtv, QK, Vt);

    k_scores256<<<dim3(36, 1, 4), 512, 0, stream>>>(QK, S);
    k_softmax<<<2048, 256, 0, stream>>>(S);
    k_pv<<<dim3(8, 8, 4), 512, 0, stream>>>(S, Vt, out);
}

// Round 10
// 219.133 us; speedup vs baseline: 1.0463x; 1.0463x over previous
//
#include <hip/hip_runtime.h>
#include <cstdint>

// ---------- types ----------
typedef __attribute__((ext_vector_type(4))) float f32x4;
typedef __attribute__((ext_vector_type(8))) __bf16 bf16x8;
typedef __attribute__((ext_vector_type(8))) unsigned short u16x8;

// ---------- helpers ----------
__device__ __forceinline__ unsigned short f2bf(float f) {
    union { float f; unsigned u; } v; v.f = f;
    unsigned u = v.u + 0x7FFFu + ((v.u >> 16) & 1u);   // RNE
    return (unsigned short)(u >> 16);
}
__device__ __forceinline__ float bf2f(unsigned short h) {
    union { unsigned u; float f; } v; v.u = ((unsigned)h) << 16;
    return v.f;
}

__device__ __forceinline__ void gld_lds16(const void* g, void* l) {
    auto gp = reinterpret_cast<const __attribute__((address_space(1))) unsigned int*>(
        reinterpret_cast<uintptr_t>(g));
    auto lp = reinterpret_cast<__attribute__((address_space(3))) unsigned int*>(
        reinterpret_cast<uintptr_t>(l));
    __builtin_amdgcn_global_load_lds(gp, lp, 16, 0, 0);
}

#define MFMA_BF16(a, b, c) __builtin_amdgcn_mfma_f32_16x16x32_bf16((a), (b), (c), 0, 0, 0)

// ================= 256x256-tile 8-phase GEMM core, C = A * B^T =================
// (unchanged from round 8 — measured ~970 TF when all CUs busy)
template<int BF16OUT>
__device__ __forceinline__ void gemm256(
    const unsigned short* __restrict__ A, int lda,
    const unsigned short* __restrict__ B, int ldb,
    void* __restrict__ C, int ldc,
    int ktiles,
    unsigned short* lA, unsigned short* lB)   // each 32768 shorts (2 x 16384)
{
    const int t = threadIdx.x;
    const int l = t & 63;
    const int w = t >> 6;
    const int wm = w >> 2, wn = w & 3;         // 2(M) x 4(N)

    f32x4 acc[8][4];
#pragma unroll
    for (int i = 0; i < 8; ++i)
#pragma unroll
        for (int j = 0; j < 4; ++j)
#pragma unroll
            for (int e = 0; e < 4; ++e) acc[i][j][e] = 0.f;

    auto stage = [&](const unsigned short* __restrict__ G, int ld, unsigned short* L,
                     int p, int h, int kt) {
        const int k0 = kt << 6;
#pragma unroll
        for (int i = 0; i < 2; ++i) {
            const int flat = t + (i << 9);            // 0..1023
            const int row  = (h << 7) + (flat >> 3);  // h*128 + 0..127
            const int sc   = (flat & 7) ^ (row & 7);  // pre-swizzled source chunk
            gld_lds16(G + (size_t)row * ld + k0 + (sc << 3),
                      L + (p << 14) + (h << 13) + (flat << 3));
        }
    };

    auto rdA = [&](int p, int mf, int kk) -> bf16x8 {
        const int r = (wm << 7) + (mf << 4) + (l & 15);
        const int c = (kk << 5) + ((l >> 4) << 3);
        const int ad = (((r << 6) + c) ^ ((r & 7) << 3)) + (p << 14);
        return *(const bf16x8*)(lA + ad);
    };
    auto rdB = [&](int p, int nf, int kk) -> bf16x8 {
        const int r = (wn << 6) + (nf << 4) + (l & 15);
        const int c = (kk << 5) + ((l >> 4) << 3);
        const int ad = (((r << 6) + c) ^ ((r & 7) << 3)) + (p << 14);
        return *(const bf16x8*)(lB + ad);
    };

    // prologue: B(0),A(0) -> buf0 ; B(1) -> buf1. vmcnt(4) leaves B(1) pair in flight.
    const int kt1 = (ktiles > 1) ? 1 : 0;
    stage(B, ldb, lB, 0, 0, 0); stage(B, ldb, lB, 0, 1, 0);
    stage(A, lda, lA, 0, 0, 0); stage(A, lda, lA, 0, 1, 0);
    stage(B, ldb, lB, 1, 0, kt1); stage(B, ldb, lB, 1, 1, kt1);
    asm volatile("s_waitcnt vmcnt(4)" ::: "memory");
    __builtin_amdgcn_s_barrier();

#define MMA_PHASE(MF0, A00, A01, A10, A11)                                    \
    __builtin_amdgcn_s_setprio(1);                                            \
    _Pragma("unroll")                                                         \
    for (int nf = 0; nf < 4; ++nf) {                                          \
        acc[MF0][nf]     = MFMA_BF16(A00, bq[nf][0], acc[MF0][nf]);           \
        acc[MF0][nf]     = MFMA_BF16(A01, bq[nf][1], acc[MF0][nf]);           \
        acc[MF0 + 1][nf] = MFMA_BF16(A10, bq[nf][0], acc[MF0 + 1][nf]);       \
        acc[MF0 + 1][nf] = MFMA_BF16(A11, bq[nf][1], acc[MF0 + 1][nf]);       \
    }                                                                         \
    __builtin_amdgcn_s_setprio(0);

    for (int kt = 0; kt < ktiles; ++kt) {
        const int p = kt & 1;
        const int ktA = (kt + 1 < ktiles) ? kt + 1 : ktiles - 1;
        const int ktB = (kt + 2 < ktiles) ? kt + 2 : ktiles - 1;

        // ---- phase 0: all B frags + A mf{0,1}; stage A-h0(kt+1) ----
        bf16x8 bq[4][2];
#pragma unroll
        for (int nf = 0; nf < 4; ++nf) {
            bq[nf][0] = rdB(p, nf, 0);
            bq[nf][1] = rdB(p, nf, 1);
        }
        bf16x8 a00 = rdA(p, 0, 0), a01 = rdA(p, 0, 1);
        bf16x8 a10 = rdA(p, 1, 0), a11 = rdA(p, 1, 1);
        stage(A, lda, lA, p ^ 1, 0, ktA);
        __builtin_amdgcn_s_barrier();
        MMA_PHASE(0, a00, a01, a10, a11)
        __builtin_amdgcn_s_barrier();

        // ---- phase 1: A mf{2,3}; stage A-h1(kt+1), B-h0(kt+2) ----
        a00 = rdA(p, 2, 0); a01 = rdA(p, 2, 1);
        a10 = rdA(p, 3, 0); a11 = rdA(p, 3, 1);
        stage(A, lda, lA, p ^ 1, 1, ktA);
        stage(B, ldb, lB, p, 0, ktB);
        __builtin_amdgcn_s_barrier();
        MMA_PHASE(2, a00, a01, a10, a11)
        __builtin_amdgcn_s_barrier();

        // ---- phase 2: A mf{4,5}; stage B-h1(kt+2) ----
        a00 = rdA(p, 4, 0); a01 = rdA(p, 4, 1);
        a10 = rdA(p, 5, 0); a11 = rdA(p, 5, 1);
        stage(B, ldb, lB, p, 1, ktB);
        __builtin_amdgcn_s_barrier();
        MMA_PHASE(4, a00, a01, a10, a11)
        __builtin_amdgcn_s_barrier();

        // ---- phase 3: A mf{6,7}; vmcnt(4) then publish barrier ----
        a00 = rdA(p, 6, 0); a01 = rdA(p, 6, 1);
        a10 = rdA(p, 7, 0); a11 = rdA(p, 7, 1);
        __builtin_amdgcn_s_barrier();
        MMA_PHASE(6, a00, a01, a10, a11)
        asm volatile("s_waitcnt vmcnt(4)" ::: "memory");
        __builtin_amdgcn_s_barrier();
    }
#undef MMA_PHASE

    // epilogue: D[row][col], col=lane&15, row=(lane>>4)*4+reg (m89-verified)
#pragma unroll
    for (int mf = 0; mf < 8; ++mf)
#pragma unroll
        for (int nf = 0; nf < 4; ++nf)
#pragma unroll
            for (int j = 0; j < 4; ++j) {
                const int row = (wm << 7) + (mf << 4) + ((l >> 4) << 2) + j;
                const int col = (wn << 6) + (nf << 4) + (l & 15);
                const float v = acc[mf][nf][j];
                if (BF16OUT)
                    ((unsigned short*)C)[(size_t)row * ldc + col] = f2bf(v);
                else
                    ((float*)C)[(size_t)row * ldc + col] = v;
            }
}

// ================= 128x128 2-phase core (vt + causal PV) =================
template<int BF16OUT>
__device__ __forceinline__ void gemm8(
    const unsigned short* __restrict__ A, int lda,
    const unsigned short* __restrict__ B, int ldb,
    void* __restrict__ C, int ldc,
    int ktiles,
    unsigned short* lA, unsigned short* lB)   // each [2][128][64] shorts = 2x16KB
{
    const int t = threadIdx.x;
    const int l = t & 63;
    const int w = t >> 6;
    const int wr = w >> 1, wc = w & 1;   // 4x2 wave grid

    f32x4 acc[2][4];
#pragma unroll
    for (int i = 0; i < 2; ++i)
#pragma unroll
        for (int j = 0; j < 4; ++j)
#pragma unroll
            for (int e = 0; e < 4; ++e) acc[i][j][e] = 0.f;

    auto stage = [&](int p, int kt) {
        const int k0 = kt << 6;
#pragma unroll
        for (int i = 0; i < 2; ++i) {
            const int flat = t + (i << 9);
            const int row = flat >> 3;
            const int sc = (flat & 7) ^ (row & 7);
            gld_lds16(A + (size_t)row * lda + k0 + (sc << 3), lA + (p << 13) + (flat << 3));
            gld_lds16(B + (size_t)row * ldb + k0 + (sc << 3), lB + (p << 13) + (flat << 3));
        }
    };

    auto compute = [&](int p) {
#pragma unroll
        for (int kk = 0; kk < 2; ++kk) {
            bf16x8 af[2], bfr[4];
            const int c = (kk << 5) + ((l >> 4) << 3);
#pragma unroll
            for (int mf = 0; mf < 2; ++mf) {
                const int r = (wr << 5) + (mf << 4) + (l & 15);
                const int ad = (((r << 6) + c) ^ ((r & 7) << 3)) + (p << 13);
                af[mf] = *(const bf16x8*)(lA + ad);
            }
#pragma unroll
            for (int nf = 0; nf < 4; ++nf) {
                const int r = (wc << 6) + (nf << 4) + (l & 15);
                const int ad = (((r << 6) + c) ^ ((r & 7) << 3)) + (p << 13);
                bfr[nf] = *(const bf16x8*)(lB + ad);
            }
            __builtin_amdgcn_s_setprio(1);
#pragma unroll
            for (int mf = 0; mf < 2; ++mf)
#pragma unroll
                for (int nf = 0; nf < 4; ++nf)
                    acc[mf][nf] = MFMA_BF16(af[mf], bfr[nf], acc[mf][nf]);
            __builtin_amdgcn_s_setprio(0);
        }
    };

    stage(0, 0);
    __syncthreads();
    int p = 0;
    for (int kt = 0; kt < ktiles - 1; ++kt) {
        stage(p ^ 1, kt + 1);
        compute(p);
        __syncthreads();
        p ^= 1;
    }
    compute(p);

#pragma unroll
    for (int mf = 0; mf < 2; ++mf)
#pragma unroll
        for (int nf = 0; nf < 4; ++nf)
#pragma unroll
            for (int j = 0; j < 4; ++j) {
                const int row = (wr << 5) + (mf << 4) + ((l >> 4) << 2) + j;
                const int col = (wc << 6) + (nf << 4) + (l & 15);
                const float v = acc[mf][nf][j];
                if (BF16OUT)
                    ((unsigned short*)C)[(size_t)row * ldc + col] = f2bf(v);
                else
                    ((float*)C)[(size_t)row * ldc + col] = v;
            }
}

// ---------- wrappers ----------
// QK projection on the 256-core: 8192x2048 output = 256 tiles = EXACTLY 1 round of 256 CUs.
__global__ __launch_bounds__(512, 2) void k_qk256(
    const unsigned short* __restrict__ xb, const unsigned short* __restrict__ wtqk,
    unsigned short* __restrict__ qk)
{
    __shared__ unsigned short lA[32768], lB[32768];
    const int h = blockIdx.x;
    const int lgc = (h & 7) * 32 + (h >> 3);   // XCD swizzle, 256/8=32, bijective
    const int by = lgc >> 3, bx = lgc & 7;
    gemm256<1>(xb + (size_t)by * 256 * 1024, 1024,
               wtqk + (size_t)bx * 256 * 1024, 1024,
               qk + (size_t)by * 256 * 2048 + bx * 256, 2048,
               16, lA, lB);
}

// Vt[d][t_global] on the 128-core: 512 blocks, 2/CU (measured 808-TF class, round 5)
__global__ __launch_bounds__(512, 4) void k_gemm_vt(
    const unsigned short* __restrict__ wtv, const unsigned short* __restrict__ xb,
    unsigned short* __restrict__ vt)
{
    __shared__ unsigned short lA[16384], lB[16384];
    gemm8<1>(wtv + (size_t)blockIdx.y * 128 * 1024, 1024,
             xb + (size_t)blockIdx.x * 128 * 1024, 1024,
             vt + (size_t)blockIdx.y * 128 * 8192 + blockIdx.x * 128, 8192,
             16, lA, lB);
}

// causal scores at 256^2 tiles: triangular block index, Q = qk cols [0,1024), K = cols [1024,2048)
__global__ __launch_bounds__(512, 2) void k_scores256(
    const unsigned short* __restrict__ qk, unsigned short* __restrict__ S)
{
    __shared__ unsigned short lA[32768], lB[32768];
    const int b = blockIdx.z;
    const int tidx = blockIdx.x;               // 0..35
    int qt2 = 0;
    while ((qt2 + 1) * (qt2 + 2) / 2 <= tidx) ++qt2;
    const int kt2 = tidx - qt2 * (qt2 + 1) / 2;
    gemm256<1>(qk + ((size_t)b * 2048 + qt2 * 256) * 2048, 2048,
               qk + ((size_t)b * 2048 + kt2 * 256) * 2048 + 1024, 2048,
               S + (size_t)b * 4194304 + (size_t)qt2 * 256 * 2048 + kt2 * 256, 2048,
               16, lA, lB);
}

// PV: out[b,q][d] = sum_{t'<=q} P[b,q][t'] * Vt[d][b*2048+t']
// 512 blocks (16 q-tiles x 8 d-tiles x 4 b), longest-first (qt = 15 - y), 2 blocks/CU.
__global__ __launch_bounds__(512, 4) void k_pv(
    const unsigned short* __restrict__ P, const unsigned short* __restrict__ Vt,
    float* __restrict__ out)
{
    const int dn = blockIdx.x, b = blockIdx.z;
    const int qt = 15 - blockIdx.y;            // descending work: 32..2 BK-steps
    __shared__ unsigned short lA[16384], lB[16384];
    gemm8<0>(P + (size_t)b * 4194304 + (size_t)qt * 128 * 2048, 2048,
             Vt + (size_t)dn * 128 * 8192 + b * 2048, 8192,
             out + ((size_t)b * 2048 + qt * 128) * 1024 + dn * 128, 1024,
             (qt + 1) * 2, lA, lB);
}

// ---------- merged cast + transpose prep ----------
// blocks [0,4096): cast x -> xb (u16x8 per thread)
// blocks [4096,7168): z = (bid-4096)>>10, tile = (bid-4096)&1023:
//   z=0: Wq^T/32 -> wtqk[0:1024), z=1: Wk^T -> wtqk[1024:2048), z=2: Wv^T -> wtv
__global__ __launch_bounds__(256) void k_prep(
    const float* __restrict__ x,
    const float* __restrict__ Wq, const float* __restrict__ Wk, const float* __restrict__ Wv,
    unsigned short* __restrict__ xb,
    unsigned short* __restrict__ wtqk, unsigned short* __restrict__ wtv)
{
    __shared__ float tile[32][33];
    const int bid = blockIdx.x;
    if (bid < 4096) {
        const int i = bid * 256 + threadIdx.x;
        const float4* p = (const float4*)x + (size_t)i * 2;
        const float4 a = p[0], b = p[1];
        u16x8 r;
        r[0] = f2bf(a.x); r[1] = f2bf(a.y); r[2] = f2bf(a.z); r[3] = f2bf(a.w);
        r[4] = f2bf(b.x); r[5] = f2bf(b.y); r[6] = f2bf(b.z); r[7] = f2bf(b.w);
        *(u16x8*)(xb + (size_t)i * 8) = r;
        return;
    }
    const int rbid = bid - 4096;
    const int z = rbid >> 10, t2 = rbid & 1023;
    const float* in = (z == 0) ? Wq : (z == 1) ? Wk : Wv;
    unsigned short* out = (z < 2) ? (wtqk + (size_t)z * 1048576) : wtv;
    const float s = (z == 0) ? 0.03125f : 1.0f;
    const int bx = (t2 & 31) * 32, by = (t2 >> 5) * 32;
    const int tx = threadIdx.x & 31, ty = threadIdx.x >> 5;
    for (int r = ty; r < 32; r += 8)
        tile[r][tx] = in[(size_t)(by + r) * 1024 + bx + tx];
    __syncthreads();
    for (int r = ty; r < 32; r += 8)
        out[(size_t)(bx + r) * 1024 + by + tx] = f2bf(tile[tx][r] * s);
}

// ---------- causal row softmax over bf16 scores, in place, one wave per row ----------
__global__ __launch_bounds__(256) void k_softmax(unsigned short* __restrict__ S)
{
    const int w = threadIdx.x >> 6, l = threadIdx.x & 63;
    const int r = blockIdx.x * 4 + w;
    const int b = r >> 11, lr = r & 2047;
    unsigned short* row = S + ((size_t)b << 22) + ((size_t)lr << 11);
    const int edge = ((lr >> 7) + 1) << 7;      // 128-granular diag edge (PV reads only < edge)

    float v[32];
#pragma unroll
    for (int i = 0; i < 4; ++i) {
        const int c0 = (l << 3) + (i << 9);
        if (c0 < edge) {
            const u16x8 u = *(const u16x8*)(row + c0);
#pragma unroll
            for (int j = 0; j < 8; ++j)
                v[(i << 3) + j] = (c0 + j <= lr) ? bf2f(u[j]) : -3.0e38f;
        } else {
#pragma unroll
            for (int j = 0; j < 8; ++j) v[(i << 3) + j] = -3.0e38f;
        }
    }
    float m = v[0];
#pragma unroll
    for (int k = 1; k < 32; ++k) m = fmaxf(m, v[k]);
#pragma unroll
    for (int s = 32; s; s >>= 1) m = fmaxf(m, __shfl_xor(m, s, 64));
    float sum = 0.f;
#pragma unroll
    for (int k = 0; k < 32; ++k) { const float e = __expf(v[k] - m); v[k] = e; sum += e; }
#pragma unroll
    for (int s = 32; s; s >>= 1) sum += __shfl_xor(sum, s, 64);
    const float inv = 1.f / sum;
#pragma unroll
    for (int i = 0; i < 4; ++i) {
        const int c0 = (l << 3) + (i << 9);
        if (c0 < edge) {
            u16x8 o;
#pragma unroll
            for (int j = 0; j < 8; ++j) o[j] = f2bf(v[(i << 3) + j] * inv);
            *(u16x8*)(row + c0) = o;
        }
    }
}

// ---------- launch ----------
extern "C" void kernel_launch(void* const* d_in, const int* in_sizes, int n_in,
                              void* d_out, int out_size, void* d_ws, size_t ws_size,
                              hipStream_t stream)
{
    (void)in_sizes; (void)n_in; (void)out_size; (void)ws_size;
    const float* x  = (const float*)d_in[0];
    const float* Wq = (const float*)d_in[1];
    const float* Wk = (const float*)d_in[2];
    const float* Wv = (const float*)d_in[3];
    float* out = (float*)d_out;

    char* w = (char*)d_ws;
    unsigned short* xb   = (unsigned short*)(w);                  // 16 MiB
    unsigned short* wtqk = (unsigned short*)(w + 16777216);       //  4 MiB (Wq^T/32 | Wk^T)
    unsigned short* wtv  = (unsigned short*)(w + 20971520);       //  2 MiB
    unsigned short* QK   = (unsigned short*)(w + 23068672);       // 32 MiB (Q | K per row)
    unsigned short* Vt   = (unsigned short*)(w + 56623104);       // 16 MiB
    unsigned short* S    = (unsigned short*)(w + 73400320);       // 32 MiB (S then P in place)

    k_prep<<<7168, 256, 0, stream>>>(x, Wq, Wk, Wv, xb, wtqk, wtv);

    k_qk256  <<<256, 512, 0, stream>>>(xb, wtqk, QK);            // 1 perfect round
    k_gemm_vt<<<dim3(64, 8), 512, 0, stream>>>(wtv, xb, Vt);     // 512 blocks, 2/CU

    k_scores256<<<dim3(36, 1, 4), 512, 0, stream>>>(QK, S);      // 144 blocks, 1 round
    k_softmax<<<2048, 256, 0, stream>>>(S);
    k_pv<<<dim3(8, 16, 4), 512, 0, stream>>>(S, Vt, out);        // 512 blocks, longest-first
}